// Round 2
// baseline (334.695 us; speedup 1.0000x reference)
//
#include <hip/hip_runtime.h>

// Problem constants (from reference): T=2048, B=8, IN=1024, OUT=1024, N_MODULES=16, K=2
#define T_DIM   2048
#define B_DIM   8
#define IN_DIM  1024
#define OUT_DIM 1024
#define NMOD    16
#define KSLOT   2

// GEMM tiling (m97 structure): 128x128 block tile, BK=32, 4 waves of 64x64
#define BM 128
#define BN 128
#define BK 32

typedef __bf16 bf16x8 __attribute__((ext_vector_type(8)));
typedef float  f32x4  __attribute__((ext_vector_type(4)));
typedef unsigned short ushort8 __attribute__((ext_vector_type(8)));

typedef const __attribute__((address_space(1))) void* gptr_t;
typedef __attribute__((address_space(3))) void* lptr_t;

__device__ __forceinline__ void async_load16(const void* gp, void* lp) {
  __builtin_amdgcn_global_load_lds((gptr_t)gp, (lptr_t)lp, 16, 0, 0);
}

// fp32 -> bf16 round-to-nearest-even (data has no NaNs; skip NaN special-case)
__device__ __forceinline__ unsigned short f2bf_rne(float f) {
  unsigned int u = __float_as_uint(f);
  u += 0x7fffu + ((u >> 16) & 1u);
  return (unsigned short)(u >> 16);
}

// Streaming prepass: x [T][B][IN] fp32 -> xb same layout bf16; w -> wb bf16.
// 8 floats/thread: 2x float4 read, 1x ushort8 (16 B) write. No transpose.
__global__ __launch_bounds__(256) void convert_bf16(
    const float* __restrict__ x, const float* __restrict__ w,
    unsigned short* __restrict__ xb, unsigned short* __restrict__ wb) {
  const long tid = (long)blockIdx.x * blockDim.x + threadIdx.x;
  const long XV = (long)T_DIM * B_DIM * IN_DIM / 8;  // x vectors of 8 (multiple of 64)
  const float4* src;
  unsigned short* dst;
  long v;
  if (tid < XV) { v = tid;      src = (const float4*)x; dst = xb; }
  else          { v = tid - XV; src = (const float4*)w; dst = wb; }
  float4 a = src[2 * v];
  float4 c = src[2 * v + 1];
  ushort8 o;
  o[0] = f2bf_rne(a.x); o[1] = f2bf_rne(a.y); o[2] = f2bf_rne(a.z); o[3] = f2bf_rne(a.w);
  o[4] = f2bf_rne(c.x); o[5] = f2bf_rne(c.y); o[6] = f2bf_rne(c.z); o[7] = f2bf_rne(c.w);
  *(ushort8*)(dst + v * 8) = o;
}

// One GEMM per blockIdx.z slot (b,k): C[t,o] = sum_i xb[t][b][i] * wb[sel[b,k]][o][i]
// Both operands K-contiguous (NT GEMM) -> identical fragment loads for A and B.
//
// LDS layout is XOR-swizzled to kill ds_read_b128 bank conflicts:
//   chunk (row r, kpart c in [0,4)) lives at 16B-slot  r*4 + (c ^ ((r>>2)&3)).
// global_load_lds writes lane l -> base + l*16, so the swizzle is applied to the
// per-lane *source* address (legal: source VGPR addr is per-lane).
// Reader bank classes: slot%8 = 4*(lm&1) + (kg ^ ((lm>>2)&3)) -> all 8 groups, 2-way (free).
__global__ __launch_bounds__(256) void gemm_mod(
    const unsigned short* __restrict__ xb, const unsigned short* __restrict__ wb,
    const int* __restrict__ sel, float* __restrict__ out) {
  __shared__ alignas(16) unsigned short As[BM * BK];
  __shared__ alignas(16) unsigned short Bs[BN * BK];

  const int nt = blockIdx.x;           // OUT tile: 0..7
  const int mt = blockIdx.y;           // T tile:   0..15
  const int bk = blockIdx.z;           // 0..15 -> (b, k)
  const int b  = bk >> 1;
  const int ks = bk & 1;
  const int expert = sel[bk];          // selection[b*K + k] == sel[bk]

  const int AS = B_DIM * IN_DIM;       // A row stride in [T][B][IN] layout
  const unsigned short* A  = xb + ((long)mt * BM * B_DIM + b) * IN_DIM;
  const unsigned short* Bw = wb + ((long)expert * OUT_DIM + (long)nt * BN) * IN_DIM;

  const int tid  = threadIdx.x;
  const int lane = tid & 63;
  const int c0 = tid, c1 = tid + 256;  // each thread stages 2 chunks per tile

  // Swizzled global source offsets for the two staged chunks
  const int r0 = c0 >> 2, g0 = (c0 & 3) ^ ((r0 >> 2) & 3);
  const int r1 = c1 >> 2, g1 = (c1 & 3) ^ ((r1 >> 2) & 3);
  const long a0 = (long)r0 * AS + g0 * 8;
  const long a1 = (long)r1 * AS + g1 * 8;
  const long b0 = (long)r0 * IN_DIM + g0 * 8;
  const long b1 = (long)r1 * IN_DIM + g1 * 8;

  const int lm = lane & 15;            // MFMA m/n index
  const int kg = lane >> 4;            // MFMA k-group (0..3)
  const int ksw = ((kg ^ ((lm >> 2) & 3))) * 8;  // swizzled k-part offset (elements)

  const int wave = tid >> 6;           // 4 waves in 2x2 -> each computes 64x64
  const int wm = (wave >> 1) * 64;
  const int wn = (wave & 1) * 64;

  f32x4 acc[4][4];
  const f32x4 z = {0.f, 0.f, 0.f, 0.f};
  #pragma unroll
  for (int i = 0; i < 4; ++i)
    #pragma unroll
    for (int j = 0; j < 4; ++j) acc[i][j] = z;

  for (int kt = 0; kt < IN_DIM; kt += BK) {
    __syncthreads();                   // previous iter's ds_reads done before overwrite
    async_load16(A  + a0 + kt, &As[c0 * 8]);
    async_load16(A  + a1 + kt, &As[c1 * 8]);
    async_load16(Bw + b0 + kt, &Bs[c0 * 8]);
    async_load16(Bw + b1 + kt, &Bs[c1 * 8]);
    __syncthreads();                   // compiler drains vmcnt(0) before s_barrier

    bf16x8 af[4], bfr[4];
    #pragma unroll
    for (int mi = 0; mi < 4; ++mi)
      af[mi] = *(const bf16x8*)&As[(wm + mi * 16 + lm) * BK + ksw];
    #pragma unroll
    for (int ni = 0; ni < 4; ++ni)
      bfr[ni] = *(const bf16x8*)&Bs[(wn + ni * 16 + lm) * BK + ksw];

    #pragma unroll
    for (int mi = 0; mi < 4; ++mi)
      #pragma unroll
      for (int ni = 0; ni < 4; ++ni)
        acc[mi][ni] = __builtin_amdgcn_mfma_f32_16x16x32_bf16(af[mi], bfr[ni], acc[mi][ni], 0, 0, 0);
  }

  // Epilogue. C/D layout (m89-verified): col = lane&15, row = (lane>>4)*4 + reg
  const int row0 = mt * BM + wm + kg * 4;
  const int col0 = nt * BN + wn + lm;
  #pragma unroll
  for (int mi = 0; mi < 4; ++mi) {
    #pragma unroll
    for (int r = 0; r < 4; ++r) {
      const int t = row0 + mi * 16 + r;
      float* po = out + (long)t * (B_DIM * KSLOT * OUT_DIM)
                      + b * (KSLOT * OUT_DIM) + ks * OUT_DIM + col0;
      #pragma unroll
      for (int ni = 0; ni < 4; ++ni)
        po[ni * 16] = acc[mi][ni][r];
    }
  }
}

extern "C" void kernel_launch(void* const* d_in, const int* in_sizes, int n_in,
                              void* d_out, int out_size, void* d_ws, size_t ws_size,
                              hipStream_t stream) {
  const float* x   = (const float*)d_in[0];   // [T][B][IN] fp32
  const int*   sel = (const int*)d_in[1];     // [B][K] int32
  const float* w   = (const float*)d_in[2];   // [NMOD][OUT][IN] fp32
  float* out = (float*)d_out;                 // [T][B][K*OUT] fp32

  unsigned short* xb = (unsigned short*)d_ws;                       // 32 MiB bf16 [T][B][IN]
  unsigned short* wb = xb + (long)T_DIM * B_DIM * IN_DIM;           // 32 MiB bf16 [NMOD][OUT][IN]

  const long total_vecs =
      ((long)T_DIM * B_DIM * IN_DIM + (long)NMOD * OUT_DIM * IN_DIM) / 8;
  dim3 cgrid((unsigned)((total_vecs + 255) / 256));
  convert_bf16<<<cgrid, 256, 0, stream>>>(x, w, xb, wb);

  dim3 ggrid(OUT_DIM / BN, T_DIM / BM, B_DIM * KSLOT);
  gemm_mod<<<ggrid, 256, 0, stream>>>(xb, wb, sel, out);
}

// Round 3
// 305.714 us; speedup vs baseline: 1.0948x; 1.0948x over previous
//
#include <hip/hip_runtime.h>

// Problem constants (from reference): T=2048, B=8, IN=1024, OUT=1024, N_MODULES=16, K=2
#define T_DIM   2048
#define B_DIM   8
#define IN_DIM  1024
#define OUT_DIM 1024
#define NMOD    16
#define KSLOT   2

// GEMM tiling: 128x128 block tile, BK=64 (16 K-iterations -> half the barrier drains of BK=32)
#define BM 128
#define BN 128
#define BK 64

typedef __bf16 bf16x8 __attribute__((ext_vector_type(8)));
typedef float  f32x4  __attribute__((ext_vector_type(4)));
typedef unsigned short ushort8 __attribute__((ext_vector_type(8)));

typedef const __attribute__((address_space(1))) void* gptr_t;
typedef __attribute__((address_space(3))) void* lptr_t;

__device__ __forceinline__ void async_load16(const void* gp, void* lp) {
  __builtin_amdgcn_global_load_lds((gptr_t)gp, (lptr_t)lp, 16, 0, 0);
}

// fp32 -> bf16 round-to-nearest-even (data has no NaNs; skip NaN special-case)
__device__ __forceinline__ unsigned short f2bf_rne(float f) {
  unsigned int u = __float_as_uint(f);
  u += 0x7fffu + ((u >> 16) & 1u);
  return (unsigned short)(u >> 16);
}

// Streaming prepass: x [T][B][IN] fp32 -> xb same layout bf16; w -> wb bf16.
// 8 floats/thread: 2x float4 read, 1x ushort8 (16 B) write. No transpose.
__global__ __launch_bounds__(256) void convert_bf16(
    const float* __restrict__ x, const float* __restrict__ w,
    unsigned short* __restrict__ xb, unsigned short* __restrict__ wb) {
  const long tid = (long)blockIdx.x * blockDim.x + threadIdx.x;
  const long XV = (long)T_DIM * B_DIM * IN_DIM / 8;  // x vectors of 8 (multiple of 64)
  const float4* src;
  unsigned short* dst;
  long v;
  if (tid < XV) { v = tid;      src = (const float4*)x; dst = xb; }
  else          { v = tid - XV; src = (const float4*)w; dst = wb; }
  float4 a = src[2 * v];
  float4 c = src[2 * v + 1];
  ushort8 o;
  o[0] = f2bf_rne(a.x); o[1] = f2bf_rne(a.y); o[2] = f2bf_rne(a.z); o[3] = f2bf_rne(a.w);
  o[4] = f2bf_rne(c.x); o[5] = f2bf_rne(c.y); o[6] = f2bf_rne(c.z); o[7] = f2bf_rne(c.w);
  *(ushort8*)(dst + v * 8) = o;
}

// One GEMM per blockIdx.z slot (b,k): C[t,o] = sum_i xb[t][b][i] * wb[sel[b,k]][o][i]
// Both operands K-contiguous (NT GEMM) -> identical fragment loads for A and B.
//
// LDS: row-major [128][BK] bf16 (128 B rows), staged as 16-B chunks with a source-side
// XOR swizzle: LDS slot c holds source (row=c>>3, colgrp=(c&7)^(row&7)). Without the
// swizzle every lane of a fragment ds_read_b128 would land in one 4-bank quad
// (row stride 128 B == 32 banks). global_load_lds writes stay lane-contiguous (required).
__global__ __launch_bounds__(256) void gemm_mod(
    const unsigned short* __restrict__ xb, const unsigned short* __restrict__ wb,
    const int* __restrict__ sel, float* __restrict__ out) {
  __shared__ alignas(16) unsigned short As[BM * BK];
  __shared__ alignas(16) unsigned short Bs[BN * BK];

  const int nt = blockIdx.x;           // OUT tile: 0..7
  const int mt = blockIdx.y;           // T tile:   0..15
  const int bk = blockIdx.z;           // 0..15 -> (b, k)
  const int b  = bk >> 1;
  const int ks = bk & 1;
  const int expert = sel[bk];          // selection[b*K + k] == sel[bk]

  const int AS = B_DIM * IN_DIM;       // A row stride in [T][B][IN] layout (8192)
  const unsigned short* A  = xb + ((long)mt * BM * B_DIM + b) * IN_DIM;
  const unsigned short* Bw = wb + ((long)expert * OUT_DIM + (long)nt * BN) * IN_DIM;

  const int tid  = threadIdx.x;
  const int lane = tid & 63;

  // Staging: 1024 16-B chunks per buffer, 4 per thread per buffer per iter.
  long aoff[4], boff[4];
  int  loff[4];
  #pragma unroll
  for (int j = 0; j < 4; ++j) {
    const int c = tid + j * 256;
    const int r = c >> 3;
    const int g = (c & 7) ^ (r & 7);
    aoff[j] = (long)r * AS + g * 8;
    boff[j] = (long)r * IN_DIM + g * 8;
    loff[j] = c * 8;                   // element offset into As/Bs
  }

  const int lm = lane & 15;            // MFMA m/n index
  const int kg = lane >> 4;            // MFMA k-group (0..3)
  const int rsw = lm & 7;              // row-derived swizzle term

  const int wave = tid >> 6;           // 4 waves in 2x2 -> each computes 64x64
  const int wm = (wave >> 1) * 64;
  const int wn = (wave & 1) * 64;

  f32x4 acc[4][4];
  const f32x4 z = {0.f, 0.f, 0.f, 0.f};
  #pragma unroll
  for (int i = 0; i < 4; ++i)
    #pragma unroll
    for (int j = 0; j < 4; ++j) acc[i][j] = z;

  for (int kt = 0; kt < IN_DIM; kt += BK) {
    __syncthreads();                   // previous iter's ds_reads done before overwrite
    #pragma unroll
    for (int j = 0; j < 4; ++j) {
      async_load16(A  + aoff[j] + kt, &As[loff[j]]);
      async_load16(Bw + boff[j] + kt, &Bs[loff[j]]);
    }
    __syncthreads();                   // drains vmcnt(0) before s_barrier

    #pragma unroll
    for (int kst = 0; kst < 2; ++kst) {  // two K=32 steps inside BK=64
      bf16x8 af[4], bfr[4];
      #pragma unroll
      for (int mi = 0; mi < 4; ++mi) {
        const int row = wm + mi * 16 + lm;
        af[mi] = *(const bf16x8*)&As[(row * 8 + ((kst * 4 + kg) ^ rsw)) * 8];
      }
      #pragma unroll
      for (int ni = 0; ni < 4; ++ni) {
        const int row = wn + ni * 16 + lm;
        bfr[ni] = *(const bf16x8*)&Bs[(row * 8 + ((kst * 4 + kg) ^ rsw)) * 8];
      }
      #pragma unroll
      for (int mi = 0; mi < 4; ++mi)
        #pragma unroll
        for (int ni = 0; ni < 4; ++ni)
          acc[mi][ni] = __builtin_amdgcn_mfma_f32_16x16x32_bf16(af[mi], bfr[ni], acc[mi][ni], 0, 0, 0);
    }
  }

  // Epilogue. C/D layout (m89-verified): col = lane&15, row = (lane>>4)*4 + reg
  const int row0 = mt * BM + wm + kg * 4;
  const int col0 = nt * BN + wn + lm;
  #pragma unroll
  for (int mi = 0; mi < 4; ++mi) {
    #pragma unroll
    for (int r = 0; r < 4; ++r) {
      const int t = row0 + mi * 16 + r;
      float* po = out + (long)t * (B_DIM * KSLOT * OUT_DIM)
                      + b * (KSLOT * OUT_DIM) + ks * OUT_DIM + col0;
      #pragma unroll
      for (int ni = 0; ni < 4; ++ni)
        po[ni * 16] = acc[mi][ni][r];
    }
  }
}

extern "C" void kernel_launch(void* const* d_in, const int* in_sizes, int n_in,
                              void* d_out, int out_size, void* d_ws, size_t ws_size,
                              hipStream_t stream) {
  const float* x   = (const float*)d_in[0];   // [T][B][IN] fp32
  const int*   sel = (const int*)d_in[1];     // [B][K] int32
  const float* w   = (const float*)d_in[2];   // [NMOD][OUT][IN] fp32
  float* out = (float*)d_out;                 // [T][B][K*OUT] fp32

  unsigned short* xb = (unsigned short*)d_ws;                       // 32 MiB bf16 [T][B][IN]
  unsigned short* wb = xb + (long)T_DIM * B_DIM * IN_DIM;           // 32 MiB bf16 [NMOD][OUT][IN]

  const long total_vecs =
      ((long)T_DIM * B_DIM * IN_DIM + (long)NMOD * OUT_DIM * IN_DIM) / 8;
  dim3 cgrid((unsigned)((total_vecs + 255) / 256));
  convert_bf16<<<cgrid, 256, 0, stream>>>(x, w, xb, wb);

  dim3 ggrid(OUT_DIM / BN, T_DIM / BM, B_DIM * KSLOT);
  gemm_mod<<<ggrid, 256, 0, stream>>>(xb, wb, sel, out);
}